// Round 1
// baseline (301.087 us; speedup 1.0000x reference)
//
#include <hip/hip_runtime.h>

#define BTOT 32768

using f32x4 = __attribute__((ext_vector_type(4))) float;
using half8 = __attribute__((ext_vector_type(8))) _Float16;

typedef const __attribute__((address_space(1))) unsigned int* gptr_t;
typedef __attribute__((address_space(3))) unsigned int* lptr_t;

__device__ __forceinline__ void gl2lds16(void* lds, const void* g) {
    // async global->LDS, 16 bytes per lane (guide: m97 pattern)
    __builtin_amdgcn_global_load_lds((gptr_t)g, (lptr_t)lds, 16, 0, 0);
}

__device__ __forceinline__ float sigm(float x) {
    return __builtin_amdgcn_rcpf(1.0f + __expf(-x));
}
__device__ __forceinline__ float tanh_(float x) {
    x = fminf(fmaxf(x, -15.0f), 15.0f);
    float e = __expf(2.0f * x);
    return (e - 1.0f) * __builtin_amdgcn_rcpf(e + 1.0f);
}

// ---------------------------------------------------------------------------
// Pack: W1 (scale 32) -> hi/lo fp16 [256][64] (col 63 zero-padded);
// Wih{0,1}: select live gate rows (i, g, o; f-gate is dead since c=0), permute
// into tile order n'' = tile*192 + gate*64 + jj (tile = jj-block of 64), scale 32.
// bias = bih + bhh for the selected rows.
// ---------------------------------------------------------------------------
__global__ __launch_bounds__(256) void pack_kernel(
    const float* __restrict__ W1,
    const float* __restrict__ Wih0, const float* __restrict__ bih0, const float* __restrict__ bhh0,
    const float* __restrict__ Wih1, const float* __restrict__ bih1, const float* __restrict__ bhh1,
    _Float16* __restrict__ W1h, _Float16* __restrict__ W1l,
    _Float16* __restrict__ Wp0h, _Float16* __restrict__ Wp0l, float* __restrict__ bp0,
    _Float16* __restrict__ Wp1h, _Float16* __restrict__ Wp1l, float* __restrict__ bp1)
{
    int tid = blockIdx.x * 256 + threadIdx.x;
    if (tid < 256 * 64) {
        int n = tid >> 6, k = tid & 63;
        float v = (k < 63) ? 32.0f * W1[n * 63 + k] : 0.0f;
        _Float16 h = (_Float16)v;
        W1h[tid] = h;
        W1l[tid] = (_Float16)(v - (float)h);
    }
    int t2 = tid - 256 * 64;
    if (t2 >= 0 && t2 < 2 * 768 * 256) {
        int which = t2 / 196608;
        int rem   = t2 % 196608;
        int r = rem >> 8, k = rem & 255;
        int tile = r / 192;
        int rr = r - tile * 192;
        int g = rr >> 6, jj = rr & 63;
        int orig = ((g == 0) ? 0 : (g == 1) ? 512 : 768) + tile * 64 + jj;
        const float* W = which ? Wih1 : Wih0;
        float v = 32.0f * W[orig * 256 + k];
        _Float16 h = (_Float16)v;
        (which ? Wp1h : Wp0h)[r * 256 + k] = h;
        (which ? Wp1l : Wp0l)[r * 256 + k] = (_Float16)(v - (float)h);
        if (k == 0) {
            float bb = which ? (bih1[orig] + bhh1[orig]) : (bih0[orig] + bhh0[orig]);
            (which ? bp1 : bp0)[r] = bb;
        }
    }
}

// ---------------------------------------------------------------------------
// Prep: per-sample 63 features (gR, acc, ori), scale 16, split hi/lo fp16;
// also w = clip(weight + delta, 0, 1).
// ---------------------------------------------------------------------------
__global__ __launch_bounds__(256) void prep_kernel(
    const float* __restrict__ aM, const float* __restrict__ RMB,
    const float* __restrict__ weight, const int* __restrict__ use_flag,
    _Float16* __restrict__ Dh, _Float16* __restrict__ Dl,
    float* __restrict__ wclip, int nb)
{
    int i = blockIdx.x * 256 + threadIdx.x;
    if (i >= nb) return;
    const float* ap = aM + (size_t)i * 18;
    const float* rp = RMB + (size_t)i * 54;
    float a[18], R[54];
#pragma unroll
    for (int q = 0; q < 9; q++)  { float2 v = *(const float2*)&ap[q * 2]; a[q*2] = v.x; a[q*2+1] = v.y; }
#pragma unroll
    for (int q = 0; q < 27; q++) { float2 v = *(const float2*)&rp[q * 2]; R[q*2] = v.x; R[q*2+1] = v.y; }
    const float* R6 = R + 45;   // RMB[:,5]
    float d[64];
    d[0] = -10.0f * R6[3]; d[1] = -10.0f * R6[4]; d[2] = -10.0f * R6[5];
#pragma unroll
    for (int n = 0; n < 5; n++) {
        float v0 = a[n*3+0] - a[15], v1 = a[n*3+1] - a[16], v2 = a[n*3+2] - a[17];
#pragma unroll
        for (int k = 0; k < 3; k++)
            d[3 + n*3 + k] = v0 * R6[k] + v1 * R6[3 + k] + v2 * R6[6 + k];
    }
#pragma unroll
    for (int n = 0; n < 5; n++)
#pragma unroll
        for (int ii = 0; ii < 3; ii++)
#pragma unroll
            for (int k = 0; k < 3; k++)
                d[18 + n*9 + ii*3 + k] =
                    R6[ii] * R[n*9 + k] + R6[3 + ii] * R[n*9 + 3 + k] + R6[6 + ii] * R[n*9 + 6 + k];
    d[63] = 0.0f;
    _Float16 dh[64], dl[64];
#pragma unroll
    for (int q = 0; q < 64; q++) {
        float v = (q < 63) ? 16.0f * d[q] : 0.0f;
        _Float16 h = (_Float16)v;
        dh[q] = h; dl[q] = (_Float16)(v - (float)h);
    }
#pragma unroll
    for (int q = 0; q < 8; q++) {
        *(half8*)&Dh[(size_t)i * 64 + q * 8] = *(half8*)&dh[q * 8];
        *(half8*)&Dl[(size_t)i * 64 + q * 8] = *(half8*)&dl[q * 8];
    }
    float delta = (use_flag[0] != 0) ? (1.0f / 90.0f) : (-1.0f / 90.0f);
    wclip[i] = fminf(fmaxf(weight[i] + delta, 0.0f), 1.0f);
}

// ---------------------------------------------------------------------------
// GEMM1: x0 = relu(data @ W1^T + b1), split-fp16 (3 MFMA per product).
// BM=128, BN=128, K=64 (2 steps of 32). Output: x0 scaled by 8, hi/lo fp16.
// Scales: data*16, W1*32 -> acc/512.
// ---------------------------------------------------------------------------
__global__ __launch_bounds__(256) void gemm1_kernel(
    const _Float16* __restrict__ Dh, const _Float16* __restrict__ Dl,
    const _Float16* __restrict__ W1h, const _Float16* __restrict__ W1l,
    const float* __restrict__ b1,
    _Float16* __restrict__ Xh, _Float16* __restrict__ Xl)
{
    __shared__ _Float16 lds[4 * 128 * 32];
    _Float16* Ah = lds;
    _Float16* Al = Ah + 128 * 32;
    _Float16* Bh = Al + 128 * 32;
    _Float16* Bl = Bh + 128 * 32;
    const int t = threadIdx.x;
    const int m0 = blockIdx.x * 128, n0 = blockIdx.y * 128;
    const int lane = t & 63, wid = t >> 6;
    const int wr = wid >> 1, wc = wid & 1;
    const int r16 = lane & 15, kb = (lane >> 4) * 8;
    f32x4 acc[4][4] = {};
    for (int kt = 0; kt < 2; kt++) {
        int r = t >> 2, c = t & 3;
#pragma unroll
        for (int q = 0; q < 2; q++) {
            int row = q * 64 + r;
            gl2lds16(&Ah[row * 32 + c * 8], &Dh[(size_t)(m0 + row) * 64 + kt * 32 + c * 8]);
            gl2lds16(&Al[row * 32 + c * 8], &Dl[(size_t)(m0 + row) * 64 + kt * 32 + c * 8]);
            gl2lds16(&Bh[row * 32 + c * 8], &W1h[(n0 + row) * 64 + kt * 32 + c * 8]);
            gl2lds16(&Bl[row * 32 + c * 8], &W1l[(n0 + row) * 64 + kt * 32 + c * 8]);
        }
        asm volatile("s_waitcnt vmcnt(0)" ::: "memory");
        __syncthreads();
        half8 ah[4], al[4];
#pragma unroll
        for (int i = 0; i < 4; i++) {
            int ra = (wr * 64 + i * 16 + r16) * 32 + kb;
            ah[i] = *(const half8*)&Ah[ra];
            al[i] = *(const half8*)&Al[ra];
        }
#pragma unroll
        for (int j = 0; j < 4; j++) {
            int rb = (wc * 64 + j * 16 + r16) * 32 + kb;
            half8 bh = *(const half8*)&Bh[rb];
            half8 bl = *(const half8*)&Bl[rb];
#pragma unroll
            for (int i = 0; i < 4; i++) {
                acc[i][j] = __builtin_amdgcn_mfma_f32_16x16x32_f16(ah[i], bh, acc[i][j], 0, 0, 0);
                acc[i][j] = __builtin_amdgcn_mfma_f32_16x16x32_f16(ah[i], bl, acc[i][j], 0, 0, 0);
                acc[i][j] = __builtin_amdgcn_mfma_f32_16x16x32_f16(al[i], bh, acc[i][j], 0, 0, 0);
            }
        }
        __syncthreads();
    }
    const float inv = 1.0f / 512.0f;
#pragma unroll
    for (int i = 0; i < 4; i++)
#pragma unroll
        for (int j = 0; j < 4; j++) {
            int col = n0 + wc * 64 + j * 16 + r16;
            float bb = b1[col];
#pragma unroll
            for (int rr = 0; rr < 4; rr++) {
                int row = m0 + wr * 64 + i * 16 + (lane >> 4) * 4 + rr;
                float v = fmaxf(acc[i][j][rr] * inv + bb, 0.0f) * 8.0f;
                _Float16 h = (_Float16)v;
                Xh[(size_t)row * 256 + col] = h;
                Xl[(size_t)row * 256 + col] = (_Float16)(v - (float)h);
            }
        }
}

// ---------------------------------------------------------------------------
// LSTM GEMM: G = X @ Wp^T (+bias), split-fp16; fused activation epilogue:
// h = sig(o)*tanh(sig(i)*tanh(g)).  BM=128, BN=192 (3 gates x 64 cols),
// BK=32, 8 K-steps. Wave (wr,wc) of 2x2 holds, for each of 4 m-frags, the
// 6 n-frags {gate 0..2} x {u 0..1} at cols wc*32+u*16 -> i/g/o triples live
// in matching (lane,reg) slots => fully in-register activation.
// OUTF32=0: write h1 scaled 32 hi/lo fp16. OUTF32=1: write h2 fp32.
// ---------------------------------------------------------------------------
template<int OUTF32>
__global__ __launch_bounds__(256) void lstm_kernel(
    const _Float16* __restrict__ Xh, const _Float16* __restrict__ Xl,
    const _Float16* __restrict__ Wh, const _Float16* __restrict__ Wl,
    const float* __restrict__ bp, float inv,
    _Float16* __restrict__ Hh, _Float16* __restrict__ Hl, float* __restrict__ Hf)
{
    __shared__ _Float16 lds[(128 + 128 + 192 + 192) * 32];
    _Float16* Ah = lds;
    _Float16* Al = Ah + 128 * 32;
    _Float16* Bh = Al + 128 * 32;
    _Float16* Bl = Bh + 192 * 32;
    const int t = threadIdx.x;
    const int m0 = blockIdx.x * 128;
    const int tile = blockIdx.y;       // 0..3 : jj-block of 64
    const int n0 = tile * 192;
    const int lane = t & 63, wid = t >> 6;
    const int wr = wid >> 1, wc = wid & 1;
    const int r16 = lane & 15, kb = (lane >> 4) * 8;
    f32x4 acc[4][6] = {};
    for (int kt = 0; kt < 8; kt++) {
        int r = t >> 2, c = t & 3;
#pragma unroll
        for (int q = 0; q < 2; q++) {
            int row = q * 64 + r;
            gl2lds16(&Ah[row * 32 + c * 8], &Xh[(size_t)(m0 + row) * 256 + kt * 32 + c * 8]);
            gl2lds16(&Al[row * 32 + c * 8], &Xl[(size_t)(m0 + row) * 256 + kt * 32 + c * 8]);
        }
#pragma unroll
        for (int q = 0; q < 3; q++) {
            int row = q * 64 + r;
            gl2lds16(&Bh[row * 32 + c * 8], &Wh[(size_t)(n0 + row) * 256 + kt * 32 + c * 8]);
            gl2lds16(&Bl[row * 32 + c * 8], &Wl[(size_t)(n0 + row) * 256 + kt * 32 + c * 8]);
        }
        asm volatile("s_waitcnt vmcnt(0)" ::: "memory");
        __syncthreads();
        half8 ah[4], al[4];
#pragma unroll
        for (int i = 0; i < 4; i++) {
            int ra = (wr * 64 + i * 16 + r16) * 32 + kb;
            ah[i] = *(const half8*)&Ah[ra];
            al[i] = *(const half8*)&Al[ra];
        }
#pragma unroll
        for (int j = 0; j < 6; j++) {
            int rb = ((j >> 1) * 64 + wc * 32 + (j & 1) * 16 + r16) * 32 + kb;
            half8 bh = *(const half8*)&Bh[rb];
            half8 bl = *(const half8*)&Bl[rb];
#pragma unroll
            for (int i = 0; i < 4; i++) {
                acc[i][j] = __builtin_amdgcn_mfma_f32_16x16x32_f16(ah[i], bh, acc[i][j], 0, 0, 0);
                acc[i][j] = __builtin_amdgcn_mfma_f32_16x16x32_f16(ah[i], bl, acc[i][j], 0, 0, 0);
                acc[i][j] = __builtin_amdgcn_mfma_f32_16x16x32_f16(al[i], bh, acc[i][j], 0, 0, 0);
            }
        }
        __syncthreads();
    }
#pragma unroll
    for (int i = 0; i < 4; i++)
#pragma unroll
        for (int u = 0; u < 2; u++) {
            int coll = wc * 32 + u * 16 + r16;
            float bi = bp[n0 + coll];
            float bg = bp[n0 + 64 + coll];
            float bo = bp[n0 + 128 + coll];
            int colg = tile * 64 + coll;
#pragma unroll
            for (int rr = 0; rr < 4; rr++) {
                int row = m0 + wr * 64 + i * 16 + (lane >> 4) * 4 + rr;
                float gi = acc[i][0 + u][rr] * inv + bi;
                float gg = acc[i][2 + u][rr] * inv + bg;
                float go = acc[i][4 + u][rr] * inv + bo;
                float c2 = sigm(gi) * tanh_(gg);
                float h  = sigm(go) * tanh_(c2);
                if (OUTF32) {
                    Hf[(size_t)row * 256 + colg] = h;
                } else {
                    float v = 32.0f * h;
                    _Float16 hh = (_Float16)v;
                    Hh[(size_t)row * 256 + colg] = hh;
                    Hl[(size_t)row * 256 + colg] = (_Float16)(v - (float)hh);
                }
            }
        }
}

// ---------------------------------------------------------------------------
// Final: out = h2 @ W2^T + b2 (fp32), angles, Y-rotation of aM/wM/RMB.
// ---------------------------------------------------------------------------
__global__ __launch_bounds__(256) void final_kernel(
    const float* __restrict__ H2, const float* __restrict__ W2, const float* __restrict__ b2,
    const float* __restrict__ aM, const float* __restrict__ wM, const float* __restrict__ RMB,
    const float* __restrict__ wclip,
    float* __restrict__ outA, float* __restrict__ outW, float* __restrict__ outR, int nb)
{
    int i = blockIdx.x * 256 + threadIdx.x;
    if (i >= nb) return;
    float o[10];
#pragma unroll
    for (int j = 0; j < 10; j++) o[j] = b2[j];
    const float* h = H2 + (size_t)i * 256;
    for (int k = 0; k < 256; k += 4) {
        float4 hv = *(const float4*)&h[k];
#pragma unroll
        for (int j = 0; j < 10; j++) {
            const float* wr2 = W2 + j * 256 + k;
            o[j] += hv.x * wr2[0] + hv.y * wr2[1] + hv.z * wr2[2] + hv.w * wr2[3];
        }
    }
    float w = wclip[i];
    float cs[6], sn[6];
#pragma unroll
    for (int q = 0; q < 5; q++) {
        float ang = atan2f(o[5 + q], o[q]) * w;   // atan2(s/n, c/n) == atan2(s, c)
        float s, c;
        sincosf(ang, &s, &c);
        cs[q] = c; sn[q] = -s;                    // th = -ang
    }
    cs[5] = 1.0f; sn[5] = 0.0f;
    const float* ap = aM + (size_t)i * 18;
    const float* wp = wM + (size_t)i * 18;
    const float* rp = RMB + (size_t)i * 54;
    float* oa = outA + (size_t)i * 18;
    float* ow = outW + (size_t)i * 18;
    float* orr = outR + (size_t)i * 54;
#pragma unroll
    for (int n = 0; n < 6; n++) {
        float c = cs[n], s = sn[n];
        {
            float a0 = ap[n*3], a1 = ap[n*3+1], a2 = ap[n*3+2];
            oa[n*3]   =  c * a0 + s * a2;
            oa[n*3+1] =  a1;
            oa[n*3+2] = -s * a0 + c * a2;
        }
        {
            float a0 = wp[n*3], a1 = wp[n*3+1], a2 = wp[n*3+2];
            ow[n*3]   =  c * a0 + s * a2;
            ow[n*3+1] =  a1;
            ow[n*3+2] = -s * a0 + c * a2;
        }
#pragma unroll
        for (int k = 0; k < 3; k++) {
            float r0 = rp[n*9 + k], r1 = rp[n*9 + 3 + k], r2 = rp[n*9 + 6 + k];
            orr[n*9 + k]     =  c * r0 + s * r2;
            orr[n*9 + 3 + k] =  r1;
            orr[n*9 + 6 + k] = -s * r0 + c * r2;
        }
    }
}

// ---------------------------------------------------------------------------
extern "C" void kernel_launch(void* const* d_in, const int* in_sizes, int n_in,
                              void* d_out, int out_size, void* d_ws, size_t ws_size,
                              hipStream_t stream)
{
    const float* aM      = (const float*)d_in[0];
    const float* wM      = (const float*)d_in[1];
    const float* RMB     = (const float*)d_in[2];
    const float* weight  = (const float*)d_in[3];
    const float* W1      = (const float*)d_in[4];
    const float* b1      = (const float*)d_in[5];
    const float* Wih0    = (const float*)d_in[6];
    const float* bih0    = (const float*)d_in[8];
    const float* bhh0    = (const float*)d_in[9];
    const float* Wih1    = (const float*)d_in[10];
    const float* bih1    = (const float*)d_in[12];
    const float* bhh1    = (const float*)d_in[13];
    const float* W2      = (const float*)d_in[14];
    const float* b2      = (const float*)d_in[15];
    const int*   use_flag= (const int*)d_in[16];

    char* base = (char*)d_ws;
    size_t off = 0;
    auto alloc = [&](size_t n) { void* p = base + off; off = (off + n + 255) & ~(size_t)255; return p; };

    _Float16* W1h  = (_Float16*)alloc(256 * 64 * 2);
    _Float16* W1l  = (_Float16*)alloc(256 * 64 * 2);
    _Float16* Wp0h = (_Float16*)alloc(768 * 256 * 2);
    _Float16* Wp0l = (_Float16*)alloc(768 * 256 * 2);
    _Float16* Wp1h = (_Float16*)alloc(768 * 256 * 2);
    _Float16* Wp1l = (_Float16*)alloc(768 * 256 * 2);
    float* bp0 = (float*)alloc(768 * 4);
    float* bp1 = (float*)alloc(768 * 4);
    size_t fixed = off;

    // per-sample scratch: data 256B, x0 1KB (reused as h2 fp32), h1 1KB, wclip 4B
    size_t perSample = 256 + 1024 + 1024 + 4;
    int CB = BTOT;
    while (CB > 2048 && fixed + (size_t)CB * perSample + 8192 > ws_size) CB >>= 1;

    _Float16* Dh  = (_Float16*)alloc((size_t)CB * 64 * 2);
    _Float16* Dl  = (_Float16*)alloc((size_t)CB * 64 * 2);
    _Float16* Xh  = (_Float16*)alloc((size_t)CB * 256 * 2);   // contiguous with Xl
    _Float16* Xl  = (_Float16*)alloc((size_t)CB * 256 * 2);
    _Float16* H1h = (_Float16*)alloc((size_t)CB * 256 * 2);
    _Float16* H1l = (_Float16*)alloc((size_t)CB * 256 * 2);
    float* wcl = (float*)alloc((size_t)CB * 4);
    float* H2 = (float*)Xh;   // reuse Xh+Xl region (x0 dead once lstm0 done)

    pack_kernel<<<1600, 256, 0, stream>>>(W1, Wih0, bih0, bhh0, Wih1, bih1, bhh1,
                                          W1h, W1l, Wp0h, Wp0l, bp0, Wp1h, Wp1l, bp1);

    float* outA = (float*)d_out;
    float* outW = outA + (size_t)BTOT * 18;
    float* outR = outW + (size_t)BTOT * 18;

    for (int b0 = 0; b0 < BTOT; b0 += CB) {
        prep_kernel<<<CB / 256, 256, 0, stream>>>(
            aM + (size_t)b0 * 18, RMB + (size_t)b0 * 54, weight + b0, use_flag, Dh, Dl, wcl, CB);
        gemm1_kernel<<<dim3(CB / 128, 2), 256, 0, stream>>>(Dh, Dl, W1h, W1l, b1, Xh, Xl);
        lstm_kernel<0><<<dim3(CB / 128, 4), 256, 0, stream>>>(
            Xh, Xl, Wp0h, Wp0l, bp0, 1.0f / 256.0f, H1h, H1l, nullptr);
        lstm_kernel<1><<<dim3(CB / 128, 4), 256, 0, stream>>>(
            H1h, H1l, Wp1h, Wp1l, bp1, 1.0f / 1024.0f, nullptr, nullptr, H2);
        final_kernel<<<CB / 256, 256, 0, stream>>>(
            H2, W2, b2, aM + (size_t)b0 * 18, wM + (size_t)b0 * 18, RMB + (size_t)b0 * 54,
            wcl, outA + (size_t)b0 * 18, outW + (size_t)b0 * 18, outR + (size_t)b0 * 54, CB);
    }
}

// Round 2
// 216.985 us; speedup vs baseline: 1.3876x; 1.3876x over previous
//
#include <hip/hip_runtime.h>

#define BTOT 32768

using f32x4 = __attribute__((ext_vector_type(4))) float;
using half8 = __attribute__((ext_vector_type(8))) _Float16;

typedef const __attribute__((address_space(1))) unsigned int* gptr_t;
typedef __attribute__((address_space(3))) unsigned int* lptr_t;

__device__ __forceinline__ void gl2lds16(void* lds, const void* g) {
    __builtin_amdgcn_global_load_lds((gptr_t)g, (lptr_t)lds, 16, 0, 0);
}

__device__ __forceinline__ float sigm(float x) {
    return __builtin_amdgcn_rcpf(1.0f + __expf(-x));
}
__device__ __forceinline__ float tanh_(float x) {
    x = fminf(fmaxf(x, -15.0f), 15.0f);
    float e = __expf(2.0f * x);
    return (e - 1.0f) * __builtin_amdgcn_rcpf(e + 1.0f);
}

// ---------------------------------------------------------------------------
// Pack weights, kt-major layouts:
//   W1  -> [2][256][32] per plane (scale 32, col 63 zeroed)
//   Wih -> live gates (i,g,o), tile-permuted rows r = tile*192+gate*64+jj,
//          [8][768][32] per plane (scale 32);  bias bp[768] = bih+bhh.
// ---------------------------------------------------------------------------
__global__ __launch_bounds__(256) void pack_kernel(
    const float* __restrict__ W1,
    const float* __restrict__ Wih0, const float* __restrict__ bih0, const float* __restrict__ bhh0,
    const float* __restrict__ Wih1, const float* __restrict__ bih1, const float* __restrict__ bhh1,
    _Float16* __restrict__ W1h, _Float16* __restrict__ W1l,
    _Float16* __restrict__ Wp0h, _Float16* __restrict__ Wp0l, float* __restrict__ bp0,
    _Float16* __restrict__ Wp1h, _Float16* __restrict__ Wp1l, float* __restrict__ bp1)
{
    int tid = blockIdx.x * 256 + threadIdx.x;
    if (tid < 256 * 64) {
        int n = tid >> 6, k = tid & 63;
        float v = (k < 63) ? 32.0f * W1[n * 63 + k] : 0.0f;
        _Float16 h = (_Float16)v;
        int off = (k >> 5) * 8192 + n * 32 + (k & 31);
        W1h[off] = h;
        W1l[off] = (_Float16)(v - (float)h);
    }
    int t2 = tid - 256 * 64;
    if (t2 >= 0 && t2 < 2 * 768 * 256) {
        int which = t2 / 196608;
        int rem   = t2 % 196608;
        int r = rem >> 8, k = rem & 255;
        int tile = r / 192;
        int rr = r - tile * 192;
        int g = rr >> 6, jj = rr & 63;
        int orig = ((g == 0) ? 0 : (g == 1) ? 512 : 768) + tile * 64 + jj;
        const float* W = which ? Wih1 : Wih0;
        float v = 32.0f * W[orig * 256 + k];
        _Float16 h = (_Float16)v;
        int off = (k >> 5) * 24576 + r * 32 + (k & 31);
        (which ? Wp1h : Wp0h)[off] = h;
        (which ? Wp1l : Wp0l)[off] = (_Float16)(v - (float)h);
        if (k == 0) {
            float bb = which ? (bih1[orig] + bhh1[orig]) : (bih0[orig] + bhh0[orig]);
            (which ? bp1 : bp0)[r] = bb;
        }
    }
}

// ---------------------------------------------------------------------------
// GEMM1 with fused feature-prep. BM=128, BN=128 (grid.y=2), K=64.
// Threads 0..127 compute the 63 features of sample m0+t directly into the
// A-LDS (hi/lo, kt-major, chunk-rotated to avoid write bank conflicts);
// B (= packed W1) staged via global_load_lds. One barrier total.
// Output X scaled by 8, hi/lo fp16, kt-major [8][CB][32].
// ---------------------------------------------------------------------------
__global__ __launch_bounds__(256) void gemm1_kernel(
    const float* __restrict__ aM, const float* __restrict__ RMB,
    const _Float16* __restrict__ W1h, const _Float16* __restrict__ W1l,
    const float* __restrict__ b1,
    _Float16* __restrict__ Xh, _Float16* __restrict__ Xl, int CB)
{
    __shared__ _Float16 sm[32768];   // A:[2pl][2kt][128][32]=16384, B same at 16384
    const int t = threadIdx.x;
    const int m0 = blockIdx.x * 128, n0 = blockIdx.y * 128;
    {
        int r = t >> 2, c = t & 3;
#pragma unroll
        for (int pl = 0; pl < 2; pl++) {
            const _Float16* W = pl ? W1l : W1h;
#pragma unroll
            for (int kt = 0; kt < 2; kt++)
#pragma unroll
                for (int q = 0; q < 2; q++) {
                    int row = q * 64 + r;
                    gl2lds16(&sm[16384 + pl * 8192 + kt * 4096 + row * 32 + c * 8],
                             &W[kt * 8192 + (n0 + row) * 32 + c * 8]);
                }
        }
    }
    if (t < 128) {
        int i = m0 + t;
        const float* ap = aM + (size_t)i * 18;
        const float* rp = RMB + (size_t)i * 54;
        float a[18], R[54];
#pragma unroll
        for (int q = 0; q < 9; q++)  { float2 v = *(const float2*)&ap[q * 2]; a[q*2] = v.x; a[q*2+1] = v.y; }
#pragma unroll
        for (int q = 0; q < 27; q++) { float2 v = *(const float2*)&rp[q * 2]; R[q*2] = v.x; R[q*2+1] = v.y; }
        const float* R6 = R + 45;
        float d[64];
        d[0] = -10.0f * R6[3]; d[1] = -10.0f * R6[4]; d[2] = -10.0f * R6[5];
#pragma unroll
        for (int n = 0; n < 5; n++) {
            float v0 = a[n*3+0] - a[15], v1 = a[n*3+1] - a[16], v2 = a[n*3+2] - a[17];
#pragma unroll
            for (int k = 0; k < 3; k++)
                d[3 + n*3 + k] = v0 * R6[k] + v1 * R6[3 + k] + v2 * R6[6 + k];
        }
#pragma unroll
        for (int n = 0; n < 5; n++)
#pragma unroll
            for (int ii = 0; ii < 3; ii++)
#pragma unroll
                for (int k = 0; k < 3; k++)
                    d[18 + n*9 + ii*3 + k] =
                        R6[ii] * R[n*9 + k] + R6[3 + ii] * R[n*9 + 3 + k] + R6[6 + ii] * R[n*9 + 6 + k];
        d[63] = 0.0f;
#pragma unroll
        for (int cc = 0; cc < 8; cc++) {
            int ch = (cc + t) & 7;            // rotate chunks: conflict-free writes
            int kt = ch >> 2, lc = ch & 3;
            _Float16 hh[8], ll[8];
#pragma unroll
            for (int e = 0; e < 8; e++) {
                float v = (ch * 8 + e < 63) ? 16.0f * d[ch * 8 + e] : 0.0f;
                _Float16 h = (_Float16)v;
                hh[e] = h; ll[e] = (_Float16)(v - (float)h);
            }
            *(half8*)&sm[kt * 4096 + t * 32 + lc * 8] = *(half8*)hh;
            *(half8*)&sm[8192 + kt * 4096 + t * 32 + lc * 8] = *(half8*)ll;
        }
    }
    __syncthreads();
    const int lane = t & 63, wid = t >> 6;
    const int wr = wid >> 1, wc = wid & 1;
    const int r16 = lane & 15, kb = (lane >> 4) * 8;
    f32x4 acc[4][4] = {};
#pragma unroll
    for (int kt = 0; kt < 2; kt++) {
        half8 ah[4], al[4];
#pragma unroll
        for (int i = 0; i < 4; i++) {
            int ra = kt * 4096 + (wr * 64 + i * 16 + r16) * 32 + kb;
            ah[i] = *(const half8*)&sm[ra];
            al[i] = *(const half8*)&sm[8192 + ra];
        }
#pragma unroll
        for (int j = 0; j < 4; j++) {
            int rb = kt * 4096 + (wc * 64 + j * 16 + r16) * 32 + kb;
            half8 bh = *(const half8*)&sm[16384 + rb];
            half8 bl = *(const half8*)&sm[24576 + rb];
#pragma unroll
            for (int i = 0; i < 4; i++) {
                acc[i][j] = __builtin_amdgcn_mfma_f32_16x16x32_f16(ah[i], bh, acc[i][j], 0, 0, 0);
                acc[i][j] = __builtin_amdgcn_mfma_f32_16x16x32_f16(ah[i], bl, acc[i][j], 0, 0, 0);
                acc[i][j] = __builtin_amdgcn_mfma_f32_16x16x32_f16(al[i], bh, acc[i][j], 0, 0, 0);
            }
        }
    }
    const float inv = 1.0f / 512.0f;
#pragma unroll
    for (int i = 0; i < 4; i++)
#pragma unroll
        for (int j = 0; j < 4; j++) {
            int col = n0 + wc * 64 + j * 16 + r16;
            float bb = b1[col];
            size_t kbase = (size_t)(col >> 5) * CB * 32 + (col & 31);
#pragma unroll
            for (int rr = 0; rr < 4; rr++) {
                int row = m0 + wr * 64 + i * 16 + (lane >> 4) * 4 + rr;
                float v = fmaxf(acc[i][j][rr] * inv + bb, 0.0f) * 8.0f;
                _Float16 h = (_Float16)v;
                Xh[kbase + (size_t)row * 32] = h;
                Xl[kbase + (size_t)row * 32] = (_Float16)(v - (float)h);
            }
        }
}

// ---------------------------------------------------------------------------
// LSTM GEMM, 2-phase double-buffered pipeline (raw s_barrier, no full drain
// mid-loop), split-fp16, fused activation. BM=128, BN=192 (3 gates x 64),
// BK=32, 8 K-steps. XCD-grouped 1D grid: the 4 N-tiles of one m-panel land
// on the same XCD -> X panel L2-resident. kt-major global layouts make every
// stage a contiguous 8KB copy.
// OUTF32=0: write h1 (scale 32, hi/lo fp16, kt-major).
// OUTF32=1: head fused: partial out10 = h2[:,tile] @ W2[:,tile]^T -> outP.
// ---------------------------------------------------------------------------
template<int OUTF32>
__global__ __launch_bounds__(256, 2) void lstm_kernel(
    const _Float16* __restrict__ Xh, const _Float16* __restrict__ Xl,
    const _Float16* __restrict__ Wh, const _Float16* __restrict__ Wl,
    const float* __restrict__ bp, float inv,
    _Float16* __restrict__ Hh, _Float16* __restrict__ Hl,
    const float* __restrict__ W2, float* __restrict__ outP, int CB)
{
    extern __shared__ _Float16 lds[];   // 2 x 20480 fp16 (2 x 40KB)
    const int t = threadIdx.x;
    const int nwg = gridDim.x, hb = blockIdx.x;
    const int per = nwg >> 3;
    const int L = (hb & 7) * per + (hb >> 3);   // group 4 tiles + consecutive m per XCD
    const int m0 = (L >> 2) * 128, tile = L & 3, n0 = tile * 192;
    const int sr = t >> 2, sc = t & 3;

    auto STAGE = [&](int kt, int buf) {
        _Float16* base = lds + buf * 20480;
#pragma unroll
        for (int q = 0; q < 2; q++) {
            int row = q * 64 + sr;
            gl2lds16(&base[row * 32 + sc * 8],        &Xh[(size_t)kt * CB * 32 + (size_t)(m0 + row) * 32 + sc * 8]);
            gl2lds16(&base[4096 + row * 32 + sc * 8], &Xl[(size_t)kt * CB * 32 + (size_t)(m0 + row) * 32 + sc * 8]);
        }
#pragma unroll
        for (int q = 0; q < 3; q++) {
            int row = q * 64 + sr;
            gl2lds16(&base[8192 + row * 32 + sc * 8],  &Wh[(size_t)kt * 24576 + (n0 + row) * 32 + sc * 8]);
            gl2lds16(&base[14336 + row * 32 + sc * 8], &Wl[(size_t)kt * 24576 + (n0 + row) * 32 + sc * 8]);
        }
    };

    const int lane = t & 63, wid = t >> 6;
    const int wr = wid >> 1, wc = wid & 1;
    const int r16 = lane & 15, kb = (lane >> 4) * 8;
    f32x4 acc[4][6] = {};

    STAGE(0, 0);
    asm volatile("s_waitcnt vmcnt(0)" ::: "memory");
    __builtin_amdgcn_s_barrier();
    __builtin_amdgcn_sched_barrier(0);
#pragma unroll
    for (int kt = 0; kt < 8; kt++) {
        const int cur = kt & 1;
        if (kt < 7) STAGE(kt + 1, cur ^ 1);
        const _Float16* B = lds + cur * 20480;
        half8 ah[4], al[4];
#pragma unroll
        for (int i = 0; i < 4; i++) {
            int ra = (wr * 64 + i * 16 + r16) * 32 + kb;
            ah[i] = *(const half8*)&B[ra];
            al[i] = *(const half8*)&B[4096 + ra];
        }
        __builtin_amdgcn_s_setprio(1);
#pragma unroll
        for (int j = 0; j < 6; j++) {
            int rb = 8192 + ((j >> 1) * 64 + wc * 32 + (j & 1) * 16 + r16) * 32 + kb;
            half8 bh = *(const half8*)&B[rb];
            half8 bl = *(const half8*)&B[rb + 6144];
#pragma unroll
            for (int i = 0; i < 4; i++) {
                acc[i][j] = __builtin_amdgcn_mfma_f32_16x16x32_f16(ah[i], bh, acc[i][j], 0, 0, 0);
                acc[i][j] = __builtin_amdgcn_mfma_f32_16x16x32_f16(ah[i], bl, acc[i][j], 0, 0, 0);
                acc[i][j] = __builtin_amdgcn_mfma_f32_16x16x32_f16(al[i], bh, acc[i][j], 0, 0, 0);
            }
        }
        __builtin_amdgcn_s_setprio(0);
        if (kt < 7) {
            asm volatile("s_waitcnt vmcnt(0)" ::: "memory");   // next tile landed
            __builtin_amdgcn_s_barrier();
            __builtin_amdgcn_sched_barrier(0);
        }
    }

    if (OUTF32) {
        float* fb  = (float*)lds;          // h2 [128][64] (reuses buf0, dead)
        float* W2s = fb + 128 * 64;        // [10][64]
#pragma unroll
        for (int i = 0; i < 4; i++)
#pragma unroll
            for (int u = 0; u < 2; u++) {
                int coll = wc * 32 + u * 16 + r16;
                float bi = bp[n0 + coll];
                float bg = bp[n0 + 64 + coll];
                float bo = bp[n0 + 128 + coll];
#pragma unroll
                for (int rr = 0; rr < 4; rr++) {
                    int rowl = wr * 64 + i * 16 + (lane >> 4) * 4 + rr;
                    float gi = acc[i][0 + u][rr] * inv + bi;
                    float gg = acc[i][2 + u][rr] * inv + bg;
                    float go = acc[i][4 + u][rr] * inv + bo;
                    float c2 = sigm(gi) * tanh_(gg);
                    fb[rowl * 64 + coll] = sigm(go) * tanh_(c2);
                }
            }
        for (int idx = t; idx < 640; idx += 256)
            W2s[idx] = W2[(idx >> 6) * 256 + tile * 64 + (idx & 63)];
        __syncthreads();
        if (t < 128) {
            float s[10];
#pragma unroll
            for (int j = 0; j < 10; j++) s[j] = 0.0f;
            for (int c = 0; c < 64; c++) {
                float hv = fb[t * 64 + c];
#pragma unroll
                for (int j = 0; j < 10; j++) s[j] += hv * W2s[j * 64 + c];
            }
            float* op = outP + ((size_t)tile * CB + m0 + t) * 10;
#pragma unroll
            for (int j = 0; j < 10; j++) op[j] = s[j];
        }
    } else {
#pragma unroll
        for (int i = 0; i < 4; i++)
#pragma unroll
            for (int u = 0; u < 2; u++) {
                int coll = wc * 32 + u * 16 + r16;
                int colg = tile * 64 + coll;
                float bi = bp[n0 + coll];
                float bg = bp[n0 + 64 + coll];
                float bo = bp[n0 + 128 + coll];
                size_t kbase = (size_t)(colg >> 5) * CB * 32 + (colg & 31);
#pragma unroll
                for (int rr = 0; rr < 4; rr++) {
                    int row = m0 + wr * 64 + i * 16 + (lane >> 4) * 4 + rr;
                    float gi = acc[i][0 + u][rr] * inv + bi;
                    float gg = acc[i][2 + u][rr] * inv + bg;
                    float go = acc[i][4 + u][rr] * inv + bo;
                    float c2 = sigm(gi) * tanh_(gg);
                    float v  = 32.0f * sigm(go) * tanh_(c2);
                    _Float16 hh = (_Float16)v;
                    Hh[kbase + (size_t)row * 32] = hh;
                    Hl[kbase + (size_t)row * 32] = (_Float16)(v - (float)hh);
                }
            }
    }
}

// ---------------------------------------------------------------------------
// Final: sum 4 tile-partials + b2, angles, Y-rotations. One thread per
// (sample, joint) for 6x the parallelism on the transcendental chain.
// ---------------------------------------------------------------------------
__global__ __launch_bounds__(256) void final_kernel(
    const float* __restrict__ outP, const float* __restrict__ b2,
    const float* __restrict__ weight, const int* __restrict__ use_flag,
    const float* __restrict__ aM, const float* __restrict__ wM, const float* __restrict__ RMB,
    float* __restrict__ outA, float* __restrict__ outW, float* __restrict__ outR, int CB)
{
    int tid = blockIdx.x * 256 + threadIdx.x;
    if (tid >= CB * 6) return;
    int i = tid / 6, n = tid - i * 6;
    float c = 1.0f, s = 0.0f;
    if (n < 5) {
        float cr = b2[n], sr = b2[5 + n];
#pragma unroll
        for (int tl = 0; tl < 4; tl++) {
            const float* op = outP + ((size_t)tl * CB + i) * 10;
            cr += op[n]; sr += op[5 + n];
        }
        float delta = (use_flag[0] != 0) ? (1.0f / 90.0f) : (-1.0f / 90.0f);
        float w = fminf(fmaxf(weight[i] + delta, 0.0f), 1.0f);
        float ang = atan2f(sr, cr) * w;     // atan2(s/n, c/n) == atan2(s, c)
        float sa, ca;
        sincosf(ang, &sa, &ca);
        c = ca; s = -sa;                    // th = -ang
    }
    {
        const float* ap = aM + (size_t)i * 18 + n * 3;
        float* oa = outA + (size_t)i * 18 + n * 3;
        float a0 = ap[0], a1 = ap[1], a2 = ap[2];
        oa[0] = c * a0 + s * a2; oa[1] = a1; oa[2] = -s * a0 + c * a2;
    }
    {
        const float* wp = wM + (size_t)i * 18 + n * 3;
        float* ow = outW + (size_t)i * 18 + n * 3;
        float a0 = wp[0], a1 = wp[1], a2 = wp[2];
        ow[0] = c * a0 + s * a2; ow[1] = a1; ow[2] = -s * a0 + c * a2;
    }
    const float* rp = RMB + (size_t)i * 54 + n * 9;
    float* orp = outR + (size_t)i * 54 + n * 9;
#pragma unroll
    for (int k = 0; k < 3; k++) {
        float r0 = rp[k], r1 = rp[3 + k], r2 = rp[6 + k];
        orp[k] = c * r0 + s * r2; orp[3 + k] = r1; orp[6 + k] = -s * r0 + c * r2;
    }
}

// ---------------------------------------------------------------------------
extern "C" void kernel_launch(void* const* d_in, const int* in_sizes, int n_in,
                              void* d_out, int out_size, void* d_ws, size_t ws_size,
                              hipStream_t stream)
{
    const float* aM      = (const float*)d_in[0];
    const float* wM      = (const float*)d_in[1];
    const float* RMB     = (const float*)d_in[2];
    const float* weight  = (const float*)d_in[3];
    const float* W1      = (const float*)d_in[4];
    const float* b1      = (const float*)d_in[5];
    const float* Wih0    = (const float*)d_in[6];
    const float* bih0    = (const float*)d_in[8];
    const float* bhh0    = (const float*)d_in[9];
    const float* Wih1    = (const float*)d_in[10];
    const float* bih1    = (const float*)d_in[12];
    const float* bhh1    = (const float*)d_in[13];
    const float* W2      = (const float*)d_in[14];
    const float* b2      = (const float*)d_in[15];
    const int*   use_flag= (const int*)d_in[16];

    char* base = (char*)d_ws;
    size_t off = 0;
    auto alloc = [&](size_t n) { void* p = base + off; off = (off + n + 255) & ~(size_t)255; return p; };

    _Float16* W1h  = (_Float16*)alloc(256 * 64 * 2);
    _Float16* W1l  = (_Float16*)alloc(256 * 64 * 2);
    _Float16* Wp0h = (_Float16*)alloc(768 * 256 * 2);
    _Float16* Wp0l = (_Float16*)alloc(768 * 256 * 2);
    _Float16* Wp1h = (_Float16*)alloc(768 * 256 * 2);
    _Float16* Wp1l = (_Float16*)alloc(768 * 256 * 2);
    float* bp0 = (float*)alloc(768 * 4);
    float* bp1 = (float*)alloc(768 * 4);
    size_t fixed = off;

    // per-sample: X 1024B + H1 1024B + outP 160B
    size_t perSample = 2208;
    int CB = BTOT;
    while (CB > 2048 && fixed + (size_t)CB * perSample + 65536 > ws_size) CB >>= 1;

    _Float16* Xh  = (_Float16*)alloc((size_t)CB * 256 * 2);
    _Float16* Xl  = (_Float16*)alloc((size_t)CB * 256 * 2);
    _Float16* H1h = (_Float16*)alloc((size_t)CB * 256 * 2);
    _Float16* H1l = (_Float16*)alloc((size_t)CB * 256 * 2);
    float* outP   = (float*)alloc((size_t)CB * 4 * 10 * 4);

    hipFuncSetAttribute((const void*)lstm_kernel<0>,
                        hipFuncAttributeMaxDynamicSharedMemorySize, 81920);
    hipFuncSetAttribute((const void*)lstm_kernel<1>,
                        hipFuncAttributeMaxDynamicSharedMemorySize, 81920);

    pack_kernel<<<1600, 256, 0, stream>>>(W1, Wih0, bih0, bhh0, Wih1, bih1, bhh1,
                                          W1h, W1l, Wp0h, Wp0l, bp0, Wp1h, Wp1l, bp1);

    float* outA = (float*)d_out;
    float* outW = outA + (size_t)BTOT * 18;
    float* outR = outW + (size_t)BTOT * 18;

    for (int b0 = 0; b0 < BTOT; b0 += CB) {
        gemm1_kernel<<<dim3(CB / 128, 2), 256, 0, stream>>>(
            aM + (size_t)b0 * 18, RMB + (size_t)b0 * 54, W1h, W1l, b1, Xh, Xl, CB);
        lstm_kernel<0><<<CB / 128 * 4, 256, 81920, stream>>>(
            Xh, Xl, Wp0h, Wp0l, bp0, 1.0f / 256.0f, H1h, H1l, nullptr, nullptr, CB);
        lstm_kernel<1><<<CB / 128 * 4, 256, 81920, stream>>>(
            H1h, H1l, Wp1h, Wp1l, bp1, 1.0f / 1024.0f, nullptr, nullptr, W2, outP, CB);
        final_kernel<<<CB * 6 / 256, 256, 0, stream>>>(
            outP, b2, weight + b0, use_flag,
            aM + (size_t)b0 * 18, wM + (size_t)b0 * 18, RMB + (size_t)b0 * 54,
            outA + (size_t)b0 * 18, outW + (size_t)b0 * 18, outR + (size_t)b0 * 54, CB);
    }
}

// Round 4
// 192.751 us; speedup vs baseline: 1.5621x; 1.1257x over previous
//
#include <hip/hip_runtime.h>

#define BTOT 32768

using f32x4 = __attribute__((ext_vector_type(4))) float;
using half8 = __attribute__((ext_vector_type(8))) _Float16;

typedef const __attribute__((address_space(1))) unsigned int* gptr_t;
typedef __attribute__((address_space(3))) unsigned int* lptr_t;

__device__ __forceinline__ void gl2lds16(void* lds, const void* g) {
    __builtin_amdgcn_global_load_lds((gptr_t)g, (lptr_t)lds, 16, 0, 0);
}

__device__ __forceinline__ float sigm(float x) {
    return __builtin_amdgcn_rcpf(1.0f + __expf(-x));
}
__device__ __forceinline__ float tanh_(float x) {
    x = fminf(fmaxf(x, -15.0f), 15.0f);
    float e = __expf(2.0f * x);
    return (e - 1.0f) * __builtin_amdgcn_rcpf(e + 1.0f);
}

// ---------------------------------------------------------------------------
// Swizzled layouts. All MFMA-consumed tensors use 128B rows of 8 x 16B
// granules, granule index XOR'd with (row&7): LDS image == global image,
// so global_load_lds stays a linear copy and ds_read_b128 is conflict-free.
//   W1sw: [2 nb][2 kt][128 n-rows][64]   (scale 32, k=63 zeroed)
//   Wsw : [4 tile][8 kt][192 rows][64]   rows = gate*64+jj, gates (i,g,o)
//   Xsw/H1sw: [8 kt][nMB][128 rows][64]
// element (row, k, plane) at row*64 + (((plane*4)+(k>>3)) ^ (row&7))*8 + (k&7)
// ---------------------------------------------------------------------------
__global__ __launch_bounds__(256) void pack_kernel(
    const float* __restrict__ W1,
    const float* __restrict__ Wih0, const float* __restrict__ bih0, const float* __restrict__ bhh0,
    const float* __restrict__ Wih1, const float* __restrict__ bih1, const float* __restrict__ bhh1,
    _Float16* __restrict__ W1sw,
    _Float16* __restrict__ W0sw, float* __restrict__ bp0,
    _Float16* __restrict__ W1sw_, float* __restrict__ bp1)
{
    int tid = blockIdx.x * 256 + threadIdx.x;
    if (tid < 256 * 64) {
        int n = tid >> 6, k = tid & 63;
        float v = (k < 63) ? 32.0f * W1[n * 63 + k] : 0.0f;
        _Float16 h = (_Float16)v;
        _Float16 l = (_Float16)(v - (float)h);
        int nb = n >> 7, r = n & 127, kt = k >> 5, kk = k & 31;
        size_t bb = (size_t)nb * 16384 + kt * 8192 + r * 64 + (kk & 7);
        int gh = (kk >> 3) ^ (r & 7);
        int gl = (4 + (kk >> 3)) ^ (r & 7);
        W1sw[bb + (gh << 3)] = h;
        W1sw[bb + (gl << 3)] = l;
    }
    int t2 = tid - 256 * 64;
    if (t2 >= 0 && t2 < 2 * 768 * 256) {
        int which = t2 / 196608;
        int rem   = t2 % 196608;
        int rlin = rem >> 8, k = rem & 255;
        int tile = rlin / 192;
        int rr = rlin - tile * 192;
        int g = rr >> 6, jj = rr & 63;
        int orig = ((g == 0) ? 0 : (g == 1) ? 512 : 768) + tile * 64 + jj;
        const float* W = which ? Wih1 : Wih0;
        float v = 32.0f * W[orig * 256 + k];
        _Float16 h = (_Float16)v;
        _Float16 l = (_Float16)(v - (float)h);
        int kt = k >> 5, kk = k & 31;
        _Float16* Wd = which ? W1sw_ : W0sw;
        size_t bb = (size_t)(tile * 8 + kt) * 12288 + rr * 64 + (kk & 7);
        int gh = (kk >> 3) ^ (rr & 7);
        int gl = (4 + (kk >> 3)) ^ (rr & 7);
        Wd[bb + (gh << 3)] = h;
        Wd[bb + (gl << 3)] = l;
        if (k == 0) {
            float bb2 = which ? (bih1[orig] + bhh1[orig]) : (bih0[orig] + bhh0[orig]);
            (which ? bp1 : bp0)[rlin] = bb2;
        }
    }
}

// ---------------------------------------------------------------------------
// GEMM1 with fused feature-prep. BM=128, BN=128 (grid.y=2), K=64.
// Threads 0..127 compute 63 features of sample m0+t, write swizzled into
// A-LDS; B staged linear (pre-swizzled global). Output X (scale 8) scattered
// into swizzled Xsw.
// ---------------------------------------------------------------------------
__global__ __launch_bounds__(256) void gemm1_kernel(
    const float* __restrict__ aM, const float* __restrict__ RMB,
    const _Float16* __restrict__ W1sw, const float* __restrict__ b1,
    _Float16* __restrict__ Xsw, int nMB)
{
    __shared__ _Float16 sm[32768];   // A:[2kt][128][64]=16384, B same
    const int t = threadIdx.x;
    const int mb = blockIdx.x, nb = blockIdx.y;
    const int m0 = mb * 128;
    {
        int o = t * 8;
#pragma unroll
        for (int it = 0; it < 8; it++)
            gl2lds16(&sm[16384 + o + it * 2048], &W1sw[(size_t)nb * 16384 + o + it * 2048]);
    }
    if (t < 128) {
        int i = m0 + t;
        const float* ap = aM + (size_t)i * 18;
        const float* rp = RMB + (size_t)i * 54;
        float a[18], R[54];
#pragma unroll
        for (int q = 0; q < 9; q++)  { float2 v = *(const float2*)&ap[q * 2]; a[q*2] = v.x; a[q*2+1] = v.y; }
#pragma unroll
        for (int q = 0; q < 27; q++) { float2 v = *(const float2*)&rp[q * 2]; R[q*2] = v.x; R[q*2+1] = v.y; }
        const float* R6 = R + 45;
        float d[64];
        d[0] = -10.0f * R6[3]; d[1] = -10.0f * R6[4]; d[2] = -10.0f * R6[5];
#pragma unroll
        for (int n = 0; n < 5; n++) {
            float v0 = a[n*3+0] - a[15], v1 = a[n*3+1] - a[16], v2 = a[n*3+2] - a[17];
#pragma unroll
            for (int k = 0; k < 3; k++)
                d[3 + n*3 + k] = v0 * R6[k] + v1 * R6[3 + k] + v2 * R6[6 + k];
        }
#pragma unroll
        for (int n = 0; n < 5; n++)
#pragma unroll
            for (int ii = 0; ii < 3; ii++)
#pragma unroll
                for (int k = 0; k < 3; k++)
                    d[18 + n*9 + ii*3 + k] =
                        R6[ii] * R[n*9 + k] + R6[3 + ii] * R[n*9 + 3 + k] + R6[6 + ii] * R[n*9 + 6 + k];
        d[63] = 0.0f;
        int sx = t & 7;
#pragma unroll
        for (int kt = 0; kt < 2; kt++)
#pragma unroll
            for (int kg = 0; kg < 4; kg++) {
                _Float16 hh[8], ll[8];
#pragma unroll
                for (int e = 0; e < 8; e++) {
                    int di = kt * 32 + kg * 8 + e;
                    float v = (di < 63) ? 16.0f * d[di] : 0.0f;
                    _Float16 h = (_Float16)v;
                    hh[e] = h; ll[e] = (_Float16)(v - (float)h);
                }
                int base = kt * 8192 + t * 64;
                *(half8*)&sm[base + ((kg ^ sx) << 3)]       = *(half8*)hh;
                *(half8*)&sm[base + (((kg + 4) ^ sx) << 3)] = *(half8*)ll;
            }
    }
    asm volatile("s_waitcnt vmcnt(0)" ::: "memory");
    __syncthreads();
    const int lane = t & 63, wid = t >> 6;
    const int wr = wid >> 1, wc = wid & 1;
    const int r16 = lane & 15, g4 = lane >> 4;
    const int sx = r16 & 7;
    const int aghi = (g4 ^ sx) << 3;
    const int aglo = ((g4 + 4) ^ sx) << 3;
    f32x4 acc[4][4] = {};
#pragma unroll
    for (int kt = 0; kt < 2; kt++) {
        half8 ah[4], al[4];
#pragma unroll
        for (int i = 0; i < 4; i++) {
            int ra = kt * 8192 + (wr * 64 + i * 16 + r16) * 64;
            ah[i] = *(const half8*)&sm[ra + aghi];
            al[i] = *(const half8*)&sm[ra + aglo];
        }
#pragma unroll
        for (int j = 0; j < 4; j++) {
            int rb = 16384 + kt * 8192 + (wc * 64 + j * 16 + r16) * 64;
            half8 bh = *(const half8*)&sm[rb + aghi];
            half8 bl = *(const half8*)&sm[rb + aglo];
#pragma unroll
            for (int i = 0; i < 4; i++) {
                acc[i][j] = __builtin_amdgcn_mfma_f32_16x16x32_f16(ah[i], bh, acc[i][j], 0, 0, 0);
                acc[i][j] = __builtin_amdgcn_mfma_f32_16x16x32_f16(ah[i], bl, acc[i][j], 0, 0, 0);
                acc[i][j] = __builtin_amdgcn_mfma_f32_16x16x32_f16(al[i], bh, acc[i][j], 0, 0, 0);
            }
        }
    }
    const float inv = 1.0f / 512.0f;
#pragma unroll
    for (int i = 0; i < 4; i++)
#pragma unroll
        for (int j = 0; j < 4; j++) {
            int col = nb * 128 + wc * 64 + j * 16 + r16;
            float bb = b1[col];
            int kth = col >> 5, kk = col & 31;
#pragma unroll
            for (int rr = 0; rr < 4; rr++) {
                int r = wr * 64 + i * 16 + g4 * 4 + rr;
                float v = fmaxf(acc[i][j][rr] * inv + bb, 0.0f) * 8.0f;
                _Float16 h = (_Float16)v;
                _Float16 l = (_Float16)(v - (float)h);
                size_t bbq = ((size_t)kth * nMB + mb) * 8192 + r * 64 + (kk & 7);
                int gh = (kk >> 3) ^ (r & 7);
                int gl = (4 + (kk >> 3)) ^ (r & 7);
                Xsw[bbq + (gh << 3)] = h;
                Xsw[bbq + (gl << 3)] = l;
            }
        }
}

// ---------------------------------------------------------------------------
// LSTM GEMM, 2-phase double-buffered, swizzled conflict-free LDS, fused
// activation. BM=128, BN=192 (3 gates x 64), BK=32, 8 K-steps. XCD-grouped
// grid. OUTF32=0: h1 (scale 32) -> swizzled H1sw. OUTF32=1: fused head
// partial out10 -> outP.
// ---------------------------------------------------------------------------
template<int OUTF32>
__global__ __launch_bounds__(256, 2) void lstm_kernel(
    const _Float16* __restrict__ Xsw, const _Float16* __restrict__ Wsw,
    const float* __restrict__ bp, float inv,
    _Float16* __restrict__ Hsw,
    const float* __restrict__ W2, float* __restrict__ outP, int nMB, int CB)
{
    extern __shared__ _Float16 lds[];   // 2 buffers x 20480 fp16 (40KB each)
    const int t = threadIdx.x;
    const int nwg = gridDim.x, hb = blockIdx.x;
    const int per = nwg >> 3;
    const int L = (hb & 7) * per + (hb >> 3);
    const int mb = L >> 2, tile = L & 3;
    const int m0 = mb * 128, n0 = tile * 192;

    auto STAGE = [&](int kt, int buf) {
        _Float16* base = lds + buf * 20480;
        const _Float16* gA = Xsw + ((size_t)kt * nMB + mb) * 8192;
        const _Float16* gB = Wsw + (size_t)(tile * 8 + kt) * 12288;
        int o = t * 8;
#pragma unroll
        for (int it = 0; it < 4; it++)
            gl2lds16(&base[o + it * 2048], &gA[o + it * 2048]);
#pragma unroll
        for (int it = 0; it < 6; it++)
            gl2lds16(&base[8192 + o + it * 2048], &gB[o + it * 2048]);
    };

    const int lane = t & 63, wid = t >> 6;
    const int wr = wid >> 1, wc = wid & 1;
    const int r16 = lane & 15, g4 = lane >> 4;
    const int sx = r16 & 7;
    const int aghi = (g4 ^ sx) << 3;
    const int aglo = ((g4 + 4) ^ sx) << 3;
    f32x4 acc[4][6] = {};

    STAGE(0, 0);
    asm volatile("s_waitcnt vmcnt(0)" ::: "memory");
    __builtin_amdgcn_s_barrier();
    __builtin_amdgcn_sched_barrier(0);
#pragma unroll
    for (int kt = 0; kt < 8; kt++) {
        const int cur = kt & 1;
        if (kt < 7) STAGE(kt + 1, cur ^ 1);
        const _Float16* B = lds + cur * 20480;
        half8 ah[4], al[4];
#pragma unroll
        for (int i = 0; i < 4; i++) {
            int ra = (wr * 64 + i * 16 + r16) * 64;
            ah[i] = *(const half8*)&B[ra + aghi];
            al[i] = *(const half8*)&B[ra + aglo];
        }
        __builtin_amdgcn_s_setprio(1);
#pragma unroll
        for (int j = 0; j < 6; j++) {
            int rb = 8192 + ((j >> 1) * 64 + wc * 32 + (j & 1) * 16 + r16) * 64;
            half8 bh = *(const half8*)&B[rb + aghi];
            half8 bl = *(const half8*)&B[rb + aglo];
#pragma unroll
            for (int i = 0; i < 4; i++) {
                acc[i][j] = __builtin_amdgcn_mfma_f32_16x16x32_f16(ah[i], bh, acc[i][j], 0, 0, 0);
                acc[i][j] = __builtin_amdgcn_mfma_f32_16x16x32_f16(ah[i], bl, acc[i][j], 0, 0, 0);
                acc[i][j] = __builtin_amdgcn_mfma_f32_16x16x32_f16(al[i], bh, acc[i][j], 0, 0, 0);
            }
        }
        __builtin_amdgcn_s_setprio(0);
        if (kt < 7) {
            asm volatile("s_waitcnt vmcnt(0)" ::: "memory");
            __builtin_amdgcn_s_barrier();
            __builtin_amdgcn_sched_barrier(0);
        }
    }

    if (OUTF32) {
        float* fb  = (float*)lds;              // [128][65] in buf0 (dead after kt6 barrier)
        float* W2s = fb + 128 * 65;            // [10][64]
#pragma unroll
        for (int i = 0; i < 4; i++)
#pragma unroll
            for (int u = 0; u < 2; u++) {
                int coll = wc * 32 + u * 16 + r16;
                float bi = bp[n0 + coll];
                float bg = bp[n0 + 64 + coll];
                float bo = bp[n0 + 128 + coll];
#pragma unroll
                for (int rr = 0; rr < 4; rr++) {
                    int rowl = wr * 64 + i * 16 + g4 * 4 + rr;
                    float gi = acc[i][0 + u][rr] * inv + bi;
                    float gg = acc[i][2 + u][rr] * inv + bg;
                    float go = acc[i][4 + u][rr] * inv + bo;
                    float c2 = sigm(gi) * tanh_(gg);
                    fb[rowl * 65 + coll] = sigm(go) * tanh_(c2);
                }
            }
        for (int idx = t; idx < 640; idx += 256)
            W2s[idx] = W2[(idx >> 6) * 256 + tile * 64 + (idx & 63)];
        __syncthreads();
        {
            int r = t & 127, jb = t >> 7;      // 5 outputs: j = jb + 2p
            float s[5] = {0, 0, 0, 0, 0};
            for (int c = 0; c < 64; c++) {
                float hv = fb[r * 65 + c];
#pragma unroll
                for (int p = 0; p < 5; p++) s[p] += hv * W2s[(jb + 2 * p) * 64 + c];
            }
            float* op = outP + ((size_t)tile * CB + m0 + r) * 10;
#pragma unroll
            for (int p = 0; p < 5; p++) op[jb + 2 * p] = s[p];
        }
    } else {
#pragma unroll
        for (int i = 0; i < 4; i++)
#pragma unroll
            for (int u = 0; u < 2; u++) {
                int coll = wc * 32 + u * 16 + r16;
                int colg = tile * 64 + coll;
                float bi = bp[n0 + coll];
                float bg = bp[n0 + 64 + coll];
                float bo = bp[n0 + 128 + coll];
                int kth = colg >> 5, kk = colg & 31;
#pragma unroll
                for (int rr = 0; rr < 4; rr++) {
                    int r = wr * 64 + i * 16 + g4 * 4 + rr;
                    float gi = acc[i][0 + u][rr] * inv + bi;
                    float gg = acc[i][2 + u][rr] * inv + bg;
                    float go = acc[i][4 + u][rr] * inv + bo;
                    float c2 = sigm(gi) * tanh_(gg);
                    float v  = 32.0f * sigm(go) * tanh_(c2);
                    _Float16 hh = (_Float16)v;
                    _Float16 ll = (_Float16)(v - (float)hh);
                    size_t bbq = ((size_t)kth * nMB + mb) * 8192 + r * 64 + (kk & 7);
                    int gh = (kk >> 3) ^ (r & 7);
                    int gl = (4 + (kk >> 3)) ^ (r & 7);
                    Hsw[bbq + (gh << 3)] = hh;
                    Hsw[bbq + (gl << 3)] = ll;
                }
            }
    }
}

// ---------------------------------------------------------------------------
// Final: sum 4 tile-partials + b2, angles, Y-rotations. One thread per
// (sample, joint).
// ---------------------------------------------------------------------------
__global__ __launch_bounds__(256) void final_kernel(
    const float* __restrict__ outP, const float* __restrict__ b2,
    const float* __restrict__ weight, const int* __restrict__ use_flag,
    const float* __restrict__ aM, const float* __restrict__ wM, const float* __restrict__ RMB,
    float* __restrict__ outA, float* __restrict__ outW, float* __restrict__ outR, int CB)
{
    int tid = blockIdx.x * 256 + threadIdx.x;
    if (tid >= CB * 6) return;
    int i = tid / 6, n = tid - i * 6;
    float c = 1.0f, s = 0.0f;
    if (n < 5) {
        float cr = b2[n], sr = b2[5 + n];
#pragma unroll
        for (int tl = 0; tl < 4; tl++) {
            const float* op = outP + ((size_t)tl * CB + i) * 10;
            cr += op[n]; sr += op[5 + n];
        }
        float delta = (use_flag[0] != 0) ? (1.0f / 90.0f) : (-1.0f / 90.0f);
        float w = fminf(fmaxf(weight[i] + delta, 0.0f), 1.0f);
        float ang = atan2f(sr, cr) * w;
        float sa, ca;
        sincosf(ang, &sa, &ca);
        c = ca; s = -sa;
    }
    {
        const float* ap = aM + (size_t)i * 18 + n * 3;
        float* oa = outA + (size_t)i * 18 + n * 3;
        float a0 = ap[0], a1 = ap[1], a2 = ap[2];
        oa[0] = c * a0 + s * a2; oa[1] = a1; oa[2] = -s * a0 + c * a2;
    }
    {
        const float* wp = wM + (size_t)i * 18 + n * 3;
        float* ow = outW + (size_t)i * 18 + n * 3;
        float a0 = wp[0], a1 = wp[1], a2 = wp[2];
        ow[0] = c * a0 + s * a2; ow[1] = a1; ow[2] = -s * a0 + c * a2;
    }
    const float* rp = RMB + (size_t)i * 54 + n * 9;
    float* orp = outR + (size_t)i * 54 + n * 9;
#pragma unroll
    for (int k = 0; k < 3; k++) {
        float r0 = rp[k], r1 = rp[3 + k], r2 = rp[6 + k];
        orp[k] = c * r0 + s * r2; orp[3 + k] = r1; orp[6 + k] = -s * r0 + c * r2;
    }
}

// ---------------------------------------------------------------------------
extern "C" void kernel_launch(void* const* d_in, const int* in_sizes, int n_in,
                              void* d_out, int out_size, void* d_ws, size_t ws_size,
                              hipStream_t stream)
{
    const float* aM      = (const float*)d_in[0];
    const float* wM      = (const float*)d_in[1];
    const float* RMB     = (const float*)d_in[2];
    const float* weight  = (const float*)d_in[3];
    const float* W1      = (const float*)d_in[4];
    const float* b1      = (const float*)d_in[5];
    const float* Wih0    = (const float*)d_in[6];
    const float* bih0    = (const float*)d_in[8];
    const float* bhh0    = (const float*)d_in[9];
    const float* Wih1    = (const float*)d_in[10];
    const float* bih1    = (const float*)d_in[12];
    const float* bhh1    = (const float*)d_in[13];
    const float* W2      = (const float*)d_in[14];
    const float* b2      = (const float*)d_in[15];
    const int*   use_flag= (const int*)d_in[16];

    char* base = (char*)d_ws;
    size_t off = 0;
    auto alloc = [&](size_t n) { void* p = base + off; off = (off + n + 255) & ~(size_t)255; return p; };

    _Float16* W1sw = (_Float16*)alloc(2 * 16384 * 2);
    _Float16* W0sw = (_Float16*)alloc(4 * 8 * 12288 * 2);
    _Float16* Wssw = (_Float16*)alloc(4 * 8 * 12288 * 2);
    float* bp0 = (float*)alloc(768 * 4);
    float* bp1 = (float*)alloc(768 * 4);
    size_t fixed = off;

    // per-sample: X 1024B + H1 1024B + outP 160B
    size_t perSample = 2208;
    int CB = BTOT;
    while (CB > 2048 && fixed + (size_t)CB * perSample + 65536 > ws_size) CB >>= 1;
    int nMB = CB / 128;

    _Float16* Xsw  = (_Float16*)alloc((size_t)CB * 1024);   // 512*CB halves
    _Float16* H1sw = (_Float16*)alloc((size_t)CB * 1024);   // 512*CB halves
    float* outP    = (float*)alloc((size_t)CB * 4 * 10 * 4);

    hipFuncSetAttribute((const void*)lstm_kernel<0>,
                        hipFuncAttributeMaxDynamicSharedMemorySize, 81920);
    hipFuncSetAttribute((const void*)lstm_kernel<1>,
                        hipFuncAttributeMaxDynamicSharedMemorySize, 81920);

    pack_kernel<<<1600, 256, 0, stream>>>(W1, Wih0, bih0, bhh0, Wih1, bih1, bhh1,
                                          W1sw, W0sw, bp0, Wssw, bp1);

    float* outA = (float*)d_out;
    float* outW = outA + (size_t)BTOT * 18;
    float* outR = outW + (size_t)BTOT * 18;

    for (int b0 = 0; b0 < BTOT; b0 += CB) {
        gemm1_kernel<<<dim3(CB / 128, 2), 256, 0, stream>>>(
            aM + (size_t)b0 * 18, RMB + (size_t)b0 * 54, W1sw, b1, Xsw, nMB);
        lstm_kernel<0><<<CB / 128 * 4, 256, 81920, stream>>>(
            Xsw, W0sw, bp0, 1.0f / 256.0f, H1sw, nullptr, nullptr, nMB, CB);
        lstm_kernel<1><<<CB / 128 * 4, 256, 81920, stream>>>(
            H1sw, Wssw, bp1, 1.0f / 1024.0f, nullptr, W2, outP, nMB, CB);
        final_kernel<<<CB * 6 / 256, 256, 0, stream>>>(
            outP, b2, weight + b0, use_flag,
            aM + (size_t)b0 * 18, wM + (size_t)b0 * 18, RMB + (size_t)b0 * 54,
            outA + (size_t)b0 * 18, outW + (size_t)b0 * 18, outR + (size_t)b0 * 54, CB);
    }
}